// Round 2
// baseline (4886.626 us; speedup 1.0000x reference)
//
#include <hip/hip_runtime.h>
#include <hip/hip_bf16.h>
#include <cstdint>

#define N_NODES 100000
#define N_EDGES 3200000
#define HID 256
#define NG 16
#define BN_EPS 1e-5f

typedef unsigned short u16;

__device__ __forceinline__ float bf2f(u16 b) {
    return __uint_as_float(((unsigned)b) << 16);
}
__device__ __forceinline__ u16 f2bf(float f) {
    unsigned u = __float_as_uint(f);
    unsigned r = (u + 0x7FFFu + ((u >> 16) & 1u)) >> 16;
    return (u16)r;
}
__device__ __forceinline__ float4 ld_bf16x4(const u16* p) {
    ushort4 u = *reinterpret_cast<const ushort4*>(p);
    float4 f;
    f.x = bf2f(u.x); f.y = bf2f(u.y); f.z = bf2f(u.z); f.w = bf2f(u.w);
    return f;
}

// ---------------- CSR build ----------------
__global__ void k_count(const int* __restrict__ coli, int* __restrict__ cnt) {
    int i = blockIdx.x * blockDim.x + threadIdx.x;
    int st = gridDim.x * blockDim.x;
    for (; i < N_EDGES; i += st) atomicAdd(&cnt[coli[i]], 1);
}

__global__ void k_dinv(const int* __restrict__ cnt, float* __restrict__ dinv) {
    int i = blockIdx.x * blockDim.x + threadIdx.x;
    if (i < N_NODES) dinv[i] = rsqrtf((float)cnt[i] + 1.0f);
}

// 1024-thread single-block scan, wave-shuffle based (3 barriers per 4096 chunk)
__global__ void k_scan(const int* __restrict__ cnt, int* __restrict__ ptr) {
    __shared__ int wsum[16];
    const int t = threadIdx.x;
    const int wv = t >> 6;
    const int ln = t & 63;
    int carry = 0;
    for (int base = 0; base < N_NODES; base += 4096) {
        int idx = base + t * 4;
        int v0 = 0, v1 = 0, v2 = 0, v3 = 0;
        if (idx + 3 < N_NODES) {
            int4 q = *reinterpret_cast<const int4*>(&cnt[idx]);
            v0 = q.x; v1 = q.y; v2 = q.z; v3 = q.w;
        } else {
            if (idx + 0 < N_NODES) v0 = cnt[idx + 0];
            if (idx + 1 < N_NODES) v1 = cnt[idx + 1];
            if (idx + 2 < N_NODES) v2 = cnt[idx + 2];
        }
        int s = v0 + v1 + v2 + v3;
        // inclusive wave scan
        int sc = s;
        for (int off = 1; off < 64; off <<= 1) {
            int u = __shfl_up(sc, off);
            if (ln >= off) sc += u;
        }
        if (ln == 63) wsum[wv] = sc;
        __syncthreads();
        if (wv == 0 && ln < 16) {
            int a = wsum[ln];
            for (int off = 1; off < 16; off <<= 1) {
                int u = __shfl_up(a, off, 16);
                if (ln >= off) a += u;
            }
            wsum[ln] = a;   // inclusive over wave totals
        }
        __syncthreads();
        int total = wsum[15];
        int excl = carry + (wv ? wsum[wv - 1] : 0) + sc - s;
        if (idx + 0 < N_NODES) ptr[idx + 0] = excl; excl += v0;
        if (idx + 1 < N_NODES) ptr[idx + 1] = excl; excl += v1;
        if (idx + 2 < N_NODES) ptr[idx + 2] = excl; excl += v2;
        if (idx + 3 < N_NODES) ptr[idx + 3] = excl;
        __syncthreads();
        carry += total;
    }
    if (t == 0) ptr[N_NODES] = carry;
}

__global__ void k_fill(const int* __restrict__ rowi, const int* __restrict__ coli,
                       const int* __restrict__ ptr, int* __restrict__ fc,
                       int* __restrict__ esrc) {
    int i = blockIdx.x * blockDim.x + threadIdx.x;
    int st = gridDim.x * blockDim.x;
    for (; i < N_EDGES; i += st) {
        int c = coli[i];
        int p = ptr[c] + atomicAdd(&fc[c], 1);
        esrc[p] = rowi[i];
    }
}

__global__ void k_batchcnt(const int* __restrict__ batch, int* __restrict__ cg) {
    int i = blockIdx.x * blockDim.x + threadIdx.x;
    if (i < N_NODES) atomicAdd(&cg[batch[i]], 1);
}

// ---------------- BN0 stats over [N,6] (f32 inputs) ----------------
__global__ void k_bn0stats(const float* __restrict__ pos, const float* __restrict__ nrm,
                           float* __restrict__ st /*12*/) {
    float s[6] = {0, 0, 0, 0, 0, 0}, q[6] = {0, 0, 0, 0, 0, 0};
    int i = blockIdx.x * blockDim.x + threadIdx.x;
    int stp = gridDim.x * blockDim.x;
    for (; i < N_NODES; i += stp) {
        float v;
        v = pos[i * 3 + 0]; s[0] += v; q[0] += v * v;
        v = pos[i * 3 + 1]; s[1] += v; q[1] += v * v;
        v = pos[i * 3 + 2]; s[2] += v; q[2] += v * v;
        v = nrm[i * 3 + 0]; s[3] += v; q[3] += v * v;
        v = nrm[i * 3 + 1]; s[4] += v; q[4] += v * v;
        v = nrm[i * 3 + 2]; s[5] += v; q[5] += v * v;
    }
#pragma unroll
    for (int k = 0; k < 6; ++k) {
        float a = s[k], b = q[k];
        for (int o = 32; o > 0; o >>= 1) { a += __shfl_down(a, o); b += __shfl_down(b, o); }
        if ((threadIdx.x & 63) == 0) { atomicAdd(&st[k], a); atomicAdd(&st[6 + k], b); }
    }
}

// ---------------- fold BN affine into weights (all f32) ----------------
// st = [sums(K), sumsq(K)]; Wf[k][c] = A[k]*W[k][c]; rv[c] = sum_k B[k]*W[k][c]
__global__ void k_fold(const float* __restrict__ W, int K,
                       const float* __restrict__ st, float invcnt,
                       const float* __restrict__ gamma, const float* __restrict__ beta,
                       float* __restrict__ Wf, float* __restrict__ rv) {
    int c = threadIdx.x;
    float acc = 0.f;
    for (int k = 0; k < K; ++k) {
        float m = st[k] * invcnt;
        float var = st[K + k] * invcnt - m * m;
        float A = gamma[k] * rsqrtf(var + BN_EPS);
        float B = beta[k] - m * A;
        float w = W[k * HID + c];
        Wf[k * HID + c] = A * w;
        acc = fmaf(B, w, acc);
    }
    rv[c] = acc;
}

// ---------------- layer-1 GEMM: [N,6](f32) @ [6,256] -> bf16 ----------------
__global__ __launch_bounds__(256) void k_gemm1(
    const float* __restrict__ pos, const float* __restrict__ nrm,
    const float* __restrict__ Wf, const float* __restrict__ rv,
    u16* __restrict__ out) {
    const int c = threadIdx.x;
    __shared__ float Ws[6 * HID];
    __shared__ float rvs[HID];
#pragma unroll
    for (int k = 0; k < 6; ++k) Ws[k * HID + c] = Wf[k * HID + c];
    rvs[c] = rv[c];
    __syncthreads();
    for (int n = blockIdx.x; n < N_NODES; n += gridDim.x) {
        float x0 = pos[n * 3 + 0], x1 = pos[n * 3 + 1], x2 = pos[n * 3 + 2];
        float x3 = nrm[n * 3 + 0], x4 = nrm[n * 3 + 1], x5 = nrm[n * 3 + 2];
        float acc = rvs[c];
        acc = fmaf(x0, Ws[0 * HID + c], acc);
        acc = fmaf(x1, Ws[1 * HID + c], acc);
        acc = fmaf(x2, Ws[2 * HID + c], acc);
        acc = fmaf(x3, Ws[3 * HID + c], acc);
        acc = fmaf(x4, Ws[4 * HID + c], acc);
        acc = fmaf(x5, Ws[5 * HID + c], acc);
        out[(size_t)n * HID + c] = f2bf(acc);
    }
}

// ---------------- main GEMM: [N,256](bf16) @ [256,256](f32) + rv -> bf16 ----------------
__global__ __launch_bounds__(256) void k_gemm(
    const u16* __restrict__ X, const float* __restrict__ Wf,
    const float* __restrict__ rv, u16* __restrict__ out) {
    __shared__ float As[64 * 128];
    const int tid = threadIdx.x;
    const int wv = tid >> 6;
    const int ln = tid & 63;
    const int row0 = blockIdx.x * 64;
    float acc[16][4];
#pragma unroll
    for (int i = 0; i < 16; ++i)
#pragma unroll
        for (int j = 0; j < 4; ++j) acc[i][j] = 0.f;

    for (int kb = 0; kb < 256; kb += 128) {
        __syncthreads();
#pragma unroll
        for (int i = 0; i < 8; ++i) {
            int idx = tid + i * 256;        // 0..2047
            int r = idx >> 5;               // 0..63
            int k4 = (idx & 31) << 2;       // 0..124
            float4 v = make_float4(0.f, 0.f, 0.f, 0.f);
            if (row0 + r < N_NODES)
                v = ld_bf16x4(&X[(size_t)(row0 + r) * HID + kb + k4]);
            *reinterpret_cast<float4*>(&As[r * 128 + k4]) = v;
        }
        __syncthreads();
#pragma unroll 2
        for (int k = 0; k < 128; ++k) {
            float4 w = *reinterpret_cast<const float4*>(&Wf[(size_t)(kb + k) * HID + ln * 4]);
#pragma unroll
            for (int i = 0; i < 16; ++i) {
                float a = As[(wv * 16 + i) * 128 + k];
                acc[i][0] = fmaf(a, w.x, acc[i][0]);
                acc[i][1] = fmaf(a, w.y, acc[i][1]);
                acc[i][2] = fmaf(a, w.z, acc[i][2]);
                acc[i][3] = fmaf(a, w.w, acc[i][3]);
            }
        }
    }
    float4 rvv = *reinterpret_cast<const float4*>(&rv[ln * 4]);
#pragma unroll
    for (int i = 0; i < 16; ++i) {
        int r = row0 + wv * 16 + i;
        if (r < N_NODES) {
            ushort4 o;
            o.x = f2bf(acc[i][0] + rvv.x);
            o.y = f2bf(acc[i][1] + rvv.y);
            o.z = f2bf(acc[i][2] + rvv.z);
            o.w = f2bf(acc[i][3] + rvv.w);
            *reinterpret_cast<ushort4*>(&out[(size_t)r * HID + ln * 4]) = o;
        }
    }
}

// ---------------- aggregation: y = relu(agg + sl*xw + bias) ----------------
__global__ __launch_bounds__(256) void k_agg(
    const u16* __restrict__ xw, const int* __restrict__ ptr,
    const int* __restrict__ esrc, const float* __restrict__ dinv,
    const float* __restrict__ bias, u16* __restrict__ y) {
    const int wv = threadIdx.x >> 6;
    const int ln = threadIdx.x & 63;
    const int n = blockIdx.x * 4 + wv;   // grid = 25000 -> exact
    const float dn = dinv[n];
    const size_t base = (size_t)n * HID + ln * 4;
    float4 v = ld_bf16x4(&xw[base]);
    const float sl = dn * dn;
    float a0 = v.x * sl, a1 = v.y * sl, a2 = v.z * sl, a3 = v.w * sl;
    const int s = ptr[n], e = ptr[n + 1];
    for (int i = s; i < e; ++i) {
        int src = esrc[i];
        float w = dinv[src] * dn;
        float4 u = ld_bf16x4(&xw[(size_t)src * HID + ln * 4]);
        a0 = fmaf(w, u.x, a0);
        a1 = fmaf(w, u.y, a1);
        a2 = fmaf(w, u.z, a2);
        a3 = fmaf(w, u.w, a3);
    }
    float4 b = *reinterpret_cast<const float4*>(&bias[ln * 4]);
    a0 = fmaxf(a0 + b.x, 0.f);
    a1 = fmaxf(a1 + b.y, 0.f);
    a2 = fmaxf(a2 + b.z, 0.f);
    a3 = fmaxf(a3 + b.w, 0.f);
    ushort4 o;
    o.x = f2bf(a0); o.y = f2bf(a1); o.z = f2bf(a2); o.w = f2bf(a3);
    *reinterpret_cast<ushort4*>(&y[base]) = o;
}

// ---------------- per-channel stats over [N,256] ----------------
__global__ void k_stats(const u16* __restrict__ y, float* __restrict__ st) {
    const int c = threadIdx.x;
    float s = 0.f, q = 0.f;
    for (int n = blockIdx.x; n < N_NODES; n += gridDim.x) {
        float v = bf2f(y[(size_t)n * HID + c]);
        s += v;
        q = fmaf(v, v, q);
    }
    atomicAdd(&st[c], s);
    atomicAdd(&st[HID + c], q);
}

// ---------------- pooled sums by graph (batch is sorted) ----------------
__global__ __launch_bounds__(256) void k_pool(
    const u16* __restrict__ y, const int* __restrict__ batch,
    float* __restrict__ ps) {
    const int c = threadIdx.x;
    int r0 = blockIdx.x * 64;
    if (r0 >= N_NODES) return;
    int rend = (r0 + 64 < N_NODES) ? r0 + 64 : N_NODES;
    int cur = batch[r0];
    float acc = 0.f;
    for (int r = r0; r < rend; ++r) {
        int g = batch[r];
        if (g != cur) {
            atomicAdd(&ps[cur * HID + c], acc);
            acc = 0.f;
            cur = g;
        }
        acc += bf2f(y[(size_t)r * HID + c]);
    }
    atomicAdd(&ps[cur * HID + c], acc);
}

// ---------------- finalize: apply BN4 affine to pooled sums, f32 out ----------------
__global__ void k_final(const float* __restrict__ ps, const int* __restrict__ cg,
                        const float* __restrict__ st, const float* __restrict__ gamma,
                        const float* __restrict__ beta, float* __restrict__ out) {
    const int c = threadIdx.x;
    const float invn = 1.0f / (float)N_NODES;
    float m = st[c] * invn;
    float var = st[HID + c] * invn - m * m;
    float A = gamma[c] * rsqrtf(var + BN_EPS);
    float B = beta[c] - m * A;
    for (int g = 0; g < NG; ++g) {
        float cn = (float)cg[g];
        float val = (A * ps[g * HID + c] + cn * B) / fmaxf(cn, 1.0f);
        out[g * HID + c] = val;
    }
}

extern "C" void kernel_launch(void* const* d_in, const int* in_sizes, int n_in,
                              void* d_out, int out_size, void* d_ws, size_t ws_size,
                              hipStream_t stream) {
    const float* pos   = (const float*)d_in[0];
    const float* nrm   = (const float*)d_in[1];
    const int*   ei    = (const int*)d_in[2];
    const int*   batch = (const int*)d_in[3];
    const float* bn0g  = (const float*)d_in[4];
    const float* bn0b  = (const float*)d_in[5];
    const float* W[4]   = {(const float*)d_in[6],  (const float*)d_in[10], (const float*)d_in[14], (const float*)d_in[18]};
    const float* bb[4]  = {(const float*)d_in[7],  (const float*)d_in[11], (const float*)d_in[15], (const float*)d_in[19]};
    const float* bg[4]  = {(const float*)d_in[8],  (const float*)d_in[12], (const float*)d_in[16], (const float*)d_in[20]};
    const float* bbt[4] = {(const float*)d_in[9],  (const float*)d_in[13], (const float*)d_in[17], (const float*)d_in[21]};

    char* wp = (char*)d_ws;
    auto alloc = [&](size_t bytes) {
        char* p = wp;
        wp += (bytes + 255) & ~(size_t)255;
        return p;
    };
    float* dinv = (float*)alloc((size_t)N_NODES * 4);
    int*   cnt  = (int*)  alloc((size_t)N_NODES * 4);
    int*   ptr  = (int*)  alloc((size_t)(N_NODES + 1) * 4);
    int*   esrc = (int*)  alloc((size_t)N_EDGES * 4);
    u16*   bufA = (u16*)  alloc((size_t)N_NODES * HID * 2);
    u16*   bufB = (u16*)  alloc((size_t)N_NODES * HID * 2);
    float* st0  = (float*)alloc(12 * 4);
    float* stL  = (float*)alloc(2 * HID * 4);
    float* Wf   = (float*)alloc((size_t)HID * HID * 4);
    float* rv   = (float*)alloc(HID * 4);
    float* ps   = (float*)alloc(NG * HID * 4);
    int*   cg   = (int*)  alloc(NG * 4);
    (void)ws_size; (void)in_sizes; (void)n_in; (void)out_size;

    const int* rowi = ei;
    const int* coli = ei + N_EDGES;

    hipMemsetAsync(cnt, 0, (size_t)N_NODES * 4, stream);
    hipMemsetAsync(st0, 0, 12 * 4, stream);
    hipMemsetAsync(ps, 0, NG * HID * 4, stream);
    hipMemsetAsync(cg, 0, NG * 4, stream);

    k_count<<<2048, 256, 0, stream>>>(coli, cnt);
    k_dinv<<<(N_NODES + 255) / 256, 256, 0, stream>>>(cnt, dinv);
    k_scan<<<1, 1024, 0, stream>>>(cnt, ptr);
    hipMemsetAsync(cnt, 0, (size_t)N_NODES * 4, stream);
    k_fill<<<2048, 256, 0, stream>>>(rowi, coli, ptr, cnt, esrc);
    k_batchcnt<<<(N_NODES + 255) / 256, 256, 0, stream>>>(batch, cg);
    k_bn0stats<<<1024, 256, 0, stream>>>(pos, nrm, st0);
    k_fold<<<1, 256, 0, stream>>>(W[0], 6, st0, 1.0f / (float)N_NODES, bn0g, bn0b, Wf, rv);
    k_gemm1<<<4096, 256, 0, stream>>>(pos, nrm, Wf, rv, bufA);

    for (int l = 0; l < 4; ++l) {
        k_agg<<<N_NODES / 4, 256, 0, stream>>>(bufA, ptr, esrc, dinv, bb[l], bufB);
        hipMemsetAsync(stL, 0, 2 * HID * 4, stream);
        k_stats<<<1024, 256, 0, stream>>>(bufB, stL);
        if (l < 3) {
            k_fold<<<1, 256, 0, stream>>>(W[l + 1], HID, stL, 1.0f / (float)N_NODES, bg[l], bbt[l], Wf, rv);
            k_gemm<<<(N_NODES + 63) / 64, 256, 0, stream>>>(bufB, Wf, rv, bufA);
        } else {
            k_pool<<<(N_NODES + 63) / 64, 256, 0, stream>>>(bufB, batch, ps);
            k_final<<<1, 256, 0, stream>>>(ps, cg, stL, bg[l], bbt[l], (float*)d_out);
        }
    }
}

// Round 3
// 3648.001 us; speedup vs baseline: 1.3395x; 1.3395x over previous
//
#include <hip/hip_runtime.h>
#include <hip/hip_bf16.h>
#include <cstdint>

#define N_NODES 100000
#define N_EDGES 3200000
#define HID 256
#define NG 16
#define BN_EPS 1e-5f

typedef unsigned short u16;
using bf16x8 = __attribute__((ext_vector_type(8))) short;
using f32x4  = __attribute__((ext_vector_type(4))) float;

__device__ __forceinline__ float bf2f(u16 b) {
    return __uint_as_float(((unsigned)b) << 16);
}
__device__ __forceinline__ u16 f2bf(float f) {
    unsigned u = __float_as_uint(f);
    unsigned r = (u + 0x7FFFu + ((u >> 16) & 1u)) >> 16;
    return (u16)r;
}
__device__ __forceinline__ float4 ld_bf16x4(const u16* p) {
    ushort4 u = *reinterpret_cast<const ushort4*>(p);
    float4 f;
    f.x = bf2f(u.x); f.y = bf2f(u.y); f.z = bf2f(u.z); f.w = bf2f(u.w);
    return f;
}

// ---------------- CSR build ----------------
__global__ void k_count(const int* __restrict__ coli, int* __restrict__ cnt) {
    int i = blockIdx.x * blockDim.x + threadIdx.x;
    int st = gridDim.x * blockDim.x;
    for (; i < N_EDGES; i += st) atomicAdd(&cnt[coli[i]], 1);
}

__global__ void k_dinv(const int* __restrict__ cnt, float* __restrict__ dinv) {
    int i = blockIdx.x * blockDim.x + threadIdx.x;
    if (i < N_NODES) dinv[i] = rsqrtf((float)cnt[i] + 1.0f);
}

// 1024-thread single-block scan, wave-shuffle based
__global__ void k_scan(const int* __restrict__ cnt, int* __restrict__ ptr) {
    __shared__ int wsum[16];
    const int t = threadIdx.x;
    const int wv = t >> 6;
    const int ln = t & 63;
    int carry = 0;
    for (int base = 0; base < N_NODES; base += 4096) {
        int idx = base + t * 4;
        int v0 = 0, v1 = 0, v2 = 0, v3 = 0;
        if (idx + 3 < N_NODES) {
            int4 q = *reinterpret_cast<const int4*>(&cnt[idx]);
            v0 = q.x; v1 = q.y; v2 = q.z; v3 = q.w;
        } else {
            if (idx + 0 < N_NODES) v0 = cnt[idx + 0];
            if (idx + 1 < N_NODES) v1 = cnt[idx + 1];
            if (idx + 2 < N_NODES) v2 = cnt[idx + 2];
        }
        int s = v0 + v1 + v2 + v3;
        int sc = s;
        for (int off = 1; off < 64; off <<= 1) {
            int u = __shfl_up(sc, off);
            if (ln >= off) sc += u;
        }
        if (ln == 63) wsum[wv] = sc;
        __syncthreads();
        if (wv == 0 && ln < 16) {
            int a = wsum[ln];
            for (int off = 1; off < 16; off <<= 1) {
                int u = __shfl_up(a, off, 16);
                if (ln >= off) a += u;
            }
            wsum[ln] = a;
        }
        __syncthreads();
        int total = wsum[15];
        int excl = carry + (wv ? wsum[wv - 1] : 0) + sc - s;
        if (idx + 0 < N_NODES) ptr[idx + 0] = excl; excl += v0;
        if (idx + 1 < N_NODES) ptr[idx + 1] = excl; excl += v1;
        if (idx + 2 < N_NODES) ptr[idx + 2] = excl; excl += v2;
        if (idx + 3 < N_NODES) ptr[idx + 3] = excl;
        __syncthreads();
        carry += total;
    }
    if (t == 0) ptr[N_NODES] = carry;
}

__global__ void k_fill(const int* __restrict__ rowi, const int* __restrict__ coli,
                       const int* __restrict__ ptr, int* __restrict__ fc,
                       int* __restrict__ esrc) {
    int i = blockIdx.x * blockDim.x + threadIdx.x;
    int st = gridDim.x * blockDim.x;
    for (; i < N_EDGES; i += st) {
        int c = coli[i];
        int p = ptr[c] + atomicAdd(&fc[c], 1);
        esrc[p] = rowi[i];
    }
}

// per-block LDS histogram -> 16 global atomics per block (batch is ~sorted,
// raw global atomics serialized ~100K deep on 16 addresses = 1.1 ms; this is ~15 us)
__global__ __launch_bounds__(256) void k_batchcnt(const int* __restrict__ batch,
                                                  int* __restrict__ cg) {
    __shared__ int h[NG];
    if (threadIdx.x < NG) h[threadIdx.x] = 0;
    __syncthreads();
    int i = blockIdx.x * blockDim.x + threadIdx.x;
    if (i < N_NODES) atomicAdd(&h[batch[i]], 1);
    __syncthreads();
    if (threadIdx.x < NG) {
        int v = h[threadIdx.x];
        if (v) atomicAdd(&cg[threadIdx.x], v);
    }
}

// ---------------- BN0 stats over [N,6] (f32 inputs) ----------------
__global__ void k_bn0stats(const float* __restrict__ pos, const float* __restrict__ nrm,
                           float* __restrict__ st /*12*/) {
    float s[6] = {0, 0, 0, 0, 0, 0}, q[6] = {0, 0, 0, 0, 0, 0};
    int i = blockIdx.x * blockDim.x + threadIdx.x;
    int stp = gridDim.x * blockDim.x;
    for (; i < N_NODES; i += stp) {
        float v;
        v = pos[i * 3 + 0]; s[0] += v; q[0] += v * v;
        v = pos[i * 3 + 1]; s[1] += v; q[1] += v * v;
        v = pos[i * 3 + 2]; s[2] += v; q[2] += v * v;
        v = nrm[i * 3 + 0]; s[3] += v; q[3] += v * v;
        v = nrm[i * 3 + 1]; s[4] += v; q[4] += v * v;
        v = nrm[i * 3 + 2]; s[5] += v; q[5] += v * v;
    }
#pragma unroll
    for (int k = 0; k < 6; ++k) {
        float a = s[k], b = q[k];
        for (int o = 32; o > 0; o >>= 1) { a += __shfl_down(a, o); b += __shfl_down(b, o); }
        if ((threadIdx.x & 63) == 0) { atomicAdd(&st[k], a); atomicAdd(&st[6 + k], b); }
    }
}

// ---------------- fold BN affine into weights, layer-1 (K=6) ----------------
__global__ void k_fold6(const float* __restrict__ W,
                        const float* __restrict__ st, float invcnt,
                        const float* __restrict__ gamma, const float* __restrict__ beta,
                        float* __restrict__ Wf, float* __restrict__ rv) {
    int c = threadIdx.x;
    float acc = 0.f;
    for (int k = 0; k < 6; ++k) {
        float m = st[k] * invcnt;
        float var = st[6 + k] * invcnt - m * m;
        float A = gamma[k] * rsqrtf(var + BN_EPS);
        float B = beta[k] - m * A;
        float w = W[k * HID + c];
        Wf[k * HID + c] = A * w;
        acc = fmaf(B, w, acc);
    }
    rv[c] = acc;
}

// ---------------- fold for K=256: f32 Wf + transposed bf16 hi/lo split ----------------
// WhiT/WloT are [col][k] so MFMA B-fragments read contiguous 16B runs.
__global__ void k_fold256(const float* __restrict__ W,
                          const float* __restrict__ st, float invcnt,
                          const float* __restrict__ gamma, const float* __restrict__ beta,
                          float* __restrict__ Wf, u16* __restrict__ WhiT,
                          u16* __restrict__ WloT, float* __restrict__ rv) {
    int c = threadIdx.x;
    float acc = 0.f;
    for (int k = 0; k < HID; ++k) {
        float m = st[k] * invcnt;
        float var = st[HID + k] * invcnt - m * m;
        float A = gamma[k] * rsqrtf(var + BN_EPS);
        float B = beta[k] - m * A;
        float w = W[k * HID + c];
        float wf = A * w;
        Wf[k * HID + c] = wf;
        u16 hi = f2bf(wf);
        WhiT[c * HID + k] = hi;
        WloT[c * HID + k] = f2bf(wf - bf2f(hi));
        acc = fmaf(B, w, acc);
    }
    rv[c] = acc;
}

// ---------------- layer-1 GEMM: [N,6](f32) @ [6,256] -> bf16 ----------------
__global__ __launch_bounds__(256) void k_gemm1(
    const float* __restrict__ pos, const float* __restrict__ nrm,
    const float* __restrict__ Wf, const float* __restrict__ rv,
    u16* __restrict__ out) {
    const int c = threadIdx.x;
    __shared__ float Ws[6 * HID];
    __shared__ float rvs[HID];
#pragma unroll
    for (int k = 0; k < 6; ++k) Ws[k * HID + c] = Wf[k * HID + c];
    rvs[c] = rv[c];
    __syncthreads();
    for (int n = blockIdx.x; n < N_NODES; n += gridDim.x) {
        float x0 = pos[n * 3 + 0], x1 = pos[n * 3 + 1], x2 = pos[n * 3 + 2];
        float x3 = nrm[n * 3 + 0], x4 = nrm[n * 3 + 1], x5 = nrm[n * 3 + 2];
        float acc = rvs[c];
        acc = fmaf(x0, Ws[0 * HID + c], acc);
        acc = fmaf(x1, Ws[1 * HID + c], acc);
        acc = fmaf(x2, Ws[2 * HID + c], acc);
        acc = fmaf(x3, Ws[3 * HID + c], acc);
        acc = fmaf(x4, Ws[4 * HID + c], acc);
        acc = fmaf(x5, Ws[5 * HID + c], acc);
        out[(size_t)n * HID + c] = f2bf(acc);
    }
}

// ---------------- MFMA GEMM: [N,256](bf16) @ (WhiT+WloT) + rv -> bf16 ----------------
// 4 waves/block, each wave owns 64 rows x 64 cols; split-weight => f32-faithful.
__global__ __launch_bounds__(256) void k_gemm_mfma(
    const u16* __restrict__ X, const u16* __restrict__ WhiT,
    const u16* __restrict__ WloT, const float* __restrict__ rv,
    u16* __restrict__ out) {
    const int tid = threadIdx.x;
    const int wv = tid >> 6;
    const int ln = tid & 63;
    const int row0 = blockIdx.x * 64;
    const int lr = ln & 15;           // A row / B col / C col within tile
    const int lk = (ln >> 4) * 8;     // k-offset within 32-k step
    const int wcol0 = wv * 64;

    f32x4 acc[4][4] = {};
    for (int kk = 0; kk < HID; kk += 32) {
        bf16x8 a[4], bh[4], bl[4];
#pragma unroll
        for (int i = 0; i < 4; ++i) {
            int r = row0 + i * 16 + lr;
            if (r >= N_NODES) r = N_NODES - 1;
            a[i] = *reinterpret_cast<const bf16x8*>(&X[(size_t)r * HID + kk + lk]);
        }
#pragma unroll
        for (int c = 0; c < 4; ++c) {
            int col = wcol0 + c * 16 + lr;
            bh[c] = *reinterpret_cast<const bf16x8*>(&WhiT[(size_t)col * HID + kk + lk]);
            bl[c] = *reinterpret_cast<const bf16x8*>(&WloT[(size_t)col * HID + kk + lk]);
        }
#pragma unroll
        for (int i = 0; i < 4; ++i)
#pragma unroll
            for (int c = 0; c < 4; ++c) {
                acc[i][c] = __builtin_amdgcn_mfma_f32_16x16x32_bf16(a[i], bh[c], acc[i][c], 0, 0, 0);
                acc[i][c] = __builtin_amdgcn_mfma_f32_16x16x32_bf16(a[i], bl[c], acc[i][c], 0, 0, 0);
            }
    }
    const int crow = (ln >> 4) * 4;   // C/D: col=lane&15, row=(lane>>4)*4+reg
#pragma unroll
    for (int c = 0; c < 4; ++c) {
        int col = wcol0 + c * 16 + lr;
        float rvc = rv[col];
#pragma unroll
        for (int i = 0; i < 4; ++i) {
#pragma unroll
            for (int rg = 0; rg < 4; ++rg) {
                int r = row0 + i * 16 + crow + rg;
                if (r < N_NODES)
                    out[(size_t)r * HID + col] = f2bf(acc[i][c][rg] + rvc);
            }
        }
    }
}

// ---------------- spot-verify MFMA result against f32 dot; sets flag on mismatch ----
__global__ void k_gverify(const u16* __restrict__ X, const float* __restrict__ Wf,
                          const float* __restrict__ rv, const u16* __restrict__ out,
                          int* __restrict__ flag) {
    int t = threadIdx.x;  // 128 threads
    int n = (t * 19391 + 7) % N_NODES;
    int c = (t * 151 + 3) & 255;
    float acc = rv[c];
    for (int k = 0; k < HID; ++k)
        acc = fmaf(bf2f(X[(size_t)n * HID + k]), Wf[k * HID + c], acc);
    float got = bf2f(out[(size_t)n * HID + c]);
    float tol = 0.02f * fabsf(acc) + 0.02f;
    if (fabsf(got - acc) > tol) atomicOr(flag, 1);
}

// ---------------- VALU fallback GEMM (runs only if flag set) ----------------
__global__ __launch_bounds__(256) void k_gemm_fb(
    const u16* __restrict__ X, const float* __restrict__ Wf,
    const float* __restrict__ rv, u16* __restrict__ out,
    const int* __restrict__ flag) {
    if (flag[0] == 0) return;
    __shared__ float As[64 * 128];
    const int tid = threadIdx.x;
    const int wv = tid >> 6;
    const int ln = tid & 63;
    const int row0 = blockIdx.x * 64;
    float acc[16][4];
#pragma unroll
    for (int i = 0; i < 16; ++i)
#pragma unroll
        for (int j = 0; j < 4; ++j) acc[i][j] = 0.f;

    for (int kb = 0; kb < 256; kb += 128) {
        __syncthreads();
#pragma unroll
        for (int i = 0; i < 8; ++i) {
            int idx = tid + i * 256;
            int r = idx >> 5;
            int k4 = (idx & 31) << 2;
            float4 v = make_float4(0.f, 0.f, 0.f, 0.f);
            if (row0 + r < N_NODES)
                v = ld_bf16x4(&X[(size_t)(row0 + r) * HID + kb + k4]);
            *reinterpret_cast<float4*>(&As[r * 128 + k4]) = v;
        }
        __syncthreads();
#pragma unroll 2
        for (int k = 0; k < 128; ++k) {
            float4 w = *reinterpret_cast<const float4*>(&Wf[(size_t)(kb + k) * HID + ln * 4]);
#pragma unroll
            for (int i = 0; i < 16; ++i) {
                float a = As[(wv * 16 + i) * 128 + k];
                acc[i][0] = fmaf(a, w.x, acc[i][0]);
                acc[i][1] = fmaf(a, w.y, acc[i][1]);
                acc[i][2] = fmaf(a, w.z, acc[i][2]);
                acc[i][3] = fmaf(a, w.w, acc[i][3]);
            }
        }
    }
    float4 rvv = *reinterpret_cast<const float4*>(&rv[ln * 4]);
#pragma unroll
    for (int i = 0; i < 16; ++i) {
        int r = row0 + wv * 16 + i;
        if (r < N_NODES) {
            ushort4 o;
            o.x = f2bf(acc[i][0] + rvv.x);
            o.y = f2bf(acc[i][1] + rvv.y);
            o.z = f2bf(acc[i][2] + rvv.z);
            o.w = f2bf(acc[i][3] + rvv.w);
            *reinterpret_cast<ushort4*>(&out[(size_t)r * HID + ln * 4]) = o;
        }
    }
}

// ---------------- aggregation: y = relu(agg + sl*xw + bias) ----------------
__global__ __launch_bounds__(256) void k_agg(
    const u16* __restrict__ xw, const int* __restrict__ ptr,
    const int* __restrict__ esrc, const float* __restrict__ dinv,
    const float* __restrict__ bias, u16* __restrict__ y) {
    const int wv = threadIdx.x >> 6;
    const int ln = threadIdx.x & 63;
    const int n = blockIdx.x * 4 + wv;
    const float dn = dinv[n];
    const size_t base = (size_t)n * HID + ln * 4;
    float4 v = ld_bf16x4(&xw[base]);
    const float sl = dn * dn;
    float a0 = v.x * sl, a1 = v.y * sl, a2 = v.z * sl, a3 = v.w * sl;
    const int s = ptr[n], e = ptr[n + 1];
    for (int i = s; i < e; ++i) {
        int src = esrc[i];
        float w = dinv[src] * dn;
        float4 u = ld_bf16x4(&xw[(size_t)src * HID + ln * 4]);
        a0 = fmaf(w, u.x, a0);
        a1 = fmaf(w, u.y, a1);
        a2 = fmaf(w, u.z, a2);
        a3 = fmaf(w, u.w, a3);
    }
    float4 b = *reinterpret_cast<const float4*>(&bias[ln * 4]);
    a0 = fmaxf(a0 + b.x, 0.f);
    a1 = fmaxf(a1 + b.y, 0.f);
    a2 = fmaxf(a2 + b.z, 0.f);
    a3 = fmaxf(a3 + b.w, 0.f);
    ushort4 o;
    o.x = f2bf(a0); o.y = f2bf(a1); o.z = f2bf(a2); o.w = f2bf(a3);
    *reinterpret_cast<ushort4*>(&y[base]) = o;
}

// ---------------- per-channel stats over [N,256] ----------------
__global__ void k_stats(const u16* __restrict__ y, float* __restrict__ st) {
    const int c = threadIdx.x;
    float s = 0.f, q = 0.f;
    for (int n = blockIdx.x; n < N_NODES; n += gridDim.x) {
        float v = bf2f(y[(size_t)n * HID + c]);
        s += v;
        q = fmaf(v, v, q);
    }
    atomicAdd(&st[c], s);
    atomicAdd(&st[HID + c], q);
}

// ---------------- pooled sums by graph (batch is sorted) ----------------
__global__ __launch_bounds__(256) void k_pool(
    const u16* __restrict__ y, const int* __restrict__ batch,
    float* __restrict__ ps) {
    const int c = threadIdx.x;
    int r0 = blockIdx.x * 64;
    if (r0 >= N_NODES) return;
    int rend = (r0 + 64 < N_NODES) ? r0 + 64 : N_NODES;
    int cur = batch[r0];
    float acc = 0.f;
    for (int r = r0; r < rend; ++r) {
        int g = batch[r];
        if (g != cur) {
            atomicAdd(&ps[cur * HID + c], acc);
            acc = 0.f;
            cur = g;
        }
        acc += bf2f(y[(size_t)r * HID + c]);
    }
    atomicAdd(&ps[cur * HID + c], acc);
}

// ---------------- finalize: apply BN4 affine to pooled sums, f32 out ----------------
__global__ void k_final(const float* __restrict__ ps, const int* __restrict__ cg,
                        const float* __restrict__ st, const float* __restrict__ gamma,
                        const float* __restrict__ beta, float* __restrict__ out) {
    const int c = threadIdx.x;
    const float invn = 1.0f / (float)N_NODES;
    float m = st[c] * invn;
    float var = st[HID + c] * invn - m * m;
    float A = gamma[c] * rsqrtf(var + BN_EPS);
    float B = beta[c] - m * A;
    for (int g = 0; g < NG; ++g) {
        float cn = (float)cg[g];
        float val = (A * ps[g * HID + c] + cn * B) / fmaxf(cn, 1.0f);
        out[g * HID + c] = val;
    }
}

extern "C" void kernel_launch(void* const* d_in, const int* in_sizes, int n_in,
                              void* d_out, int out_size, void* d_ws, size_t ws_size,
                              hipStream_t stream) {
    const float* pos   = (const float*)d_in[0];
    const float* nrm   = (const float*)d_in[1];
    const int*   ei    = (const int*)d_in[2];
    const int*   batch = (const int*)d_in[3];
    const float* bn0g  = (const float*)d_in[4];
    const float* bn0b  = (const float*)d_in[5];
    const float* W[4]   = {(const float*)d_in[6],  (const float*)d_in[10], (const float*)d_in[14], (const float*)d_in[18]};
    const float* bb[4]  = {(const float*)d_in[7],  (const float*)d_in[11], (const float*)d_in[15], (const float*)d_in[19]};
    const float* bg[4]  = {(const float*)d_in[8],  (const float*)d_in[12], (const float*)d_in[16], (const float*)d_in[20]};
    const float* bbt[4] = {(const float*)d_in[9],  (const float*)d_in[13], (const float*)d_in[17], (const float*)d_in[21]};

    char* wp = (char*)d_ws;
    auto alloc = [&](size_t bytes) {
        char* p = wp;
        wp += (bytes + 255) & ~(size_t)255;
        return p;
    };
    float* dinv = (float*)alloc((size_t)N_NODES * 4);
    int*   cnt  = (int*)  alloc((size_t)N_NODES * 4);
    int*   ptr  = (int*)  alloc((size_t)(N_NODES + 1) * 4);
    int*   esrc = (int*)  alloc((size_t)N_EDGES * 4);
    u16*   bufA = (u16*)  alloc((size_t)N_NODES * HID * 2);
    u16*   bufB = (u16*)  alloc((size_t)N_NODES * HID * 2);
    float* st0  = (float*)alloc(12 * 4);
    float* stL  = (float*)alloc(2 * HID * 4);
    float* Wf   = (float*)alloc((size_t)HID * HID * 4);
    u16*   WhiT = (u16*)  alloc((size_t)HID * HID * 2);
    u16*   WloT = (u16*)  alloc((size_t)HID * HID * 2);
    float* rv   = (float*)alloc(HID * 4);
    float* ps   = (float*)alloc(NG * HID * 4);
    int*   cg   = (int*)  alloc(NG * 4);
    int*   flag = (int*)  alloc(4);
    (void)ws_size; (void)in_sizes; (void)n_in; (void)out_size;

    const int* rowi = ei;
    const int* coli = ei + N_EDGES;

    hipMemsetAsync(cnt, 0, (size_t)N_NODES * 4, stream);
    hipMemsetAsync(st0, 0, 12 * 4, stream);
    hipMemsetAsync(ps, 0, NG * HID * 4, stream);
    hipMemsetAsync(cg, 0, NG * 4, stream);

    k_count<<<2048, 256, 0, stream>>>(coli, cnt);
    k_dinv<<<(N_NODES + 255) / 256, 256, 0, stream>>>(cnt, dinv);
    k_scan<<<1, 1024, 0, stream>>>(cnt, ptr);
    hipMemsetAsync(cnt, 0, (size_t)N_NODES * 4, stream);
    k_fill<<<2048, 256, 0, stream>>>(rowi, coli, ptr, cnt, esrc);
    k_batchcnt<<<(N_NODES + 255) / 256, 256, 0, stream>>>(batch, cg);
    k_bn0stats<<<1024, 256, 0, stream>>>(pos, nrm, st0);
    k_fold6<<<1, 256, 0, stream>>>(W[0], st0, 1.0f / (float)N_NODES, bn0g, bn0b, Wf, rv);
    k_gemm1<<<4096, 256, 0, stream>>>(pos, nrm, Wf, rv, bufA);

    for (int l = 0; l < 4; ++l) {
        k_agg<<<N_NODES / 4, 256, 0, stream>>>(bufA, ptr, esrc, dinv, bb[l], bufB);
        hipMemsetAsync(stL, 0, 2 * HID * 4, stream);
        k_stats<<<512, 256, 0, stream>>>(bufB, stL);
        if (l < 3) {
            k_fold256<<<1, 256, 0, stream>>>(W[l + 1], stL, 1.0f / (float)N_NODES,
                                             bg[l], bbt[l], Wf, WhiT, WloT, rv);
            k_gemm_mfma<<<(N_NODES + 63) / 64, 256, 0, stream>>>(bufB, WhiT, WloT, rv, bufA);
            hipMemsetAsync(flag, 0, 4, stream);
            k_gverify<<<1, 128, 0, stream>>>(bufB, Wf, rv, bufA, flag);
            k_gemm_fb<<<(N_NODES + 63) / 64, 256, 0, stream>>>(bufB, Wf, rv, bufA, flag);
        } else {
            k_pool<<<(N_NODES + 63) / 64, 256, 0, stream>>>(bufB, batch, ps);
            k_final<<<1, 256, 0, stream>>>(ps, cg, stL, bg[l], bbt[l], (float*)d_out);
        }
    }
}

// Round 4
// 2858.989 us; speedup vs baseline: 1.7092x; 1.2760x over previous
//
#include <hip/hip_runtime.h>
#include <hip/hip_bf16.h>
#include <cstdint>

#define N_NODES 100000
#define N_EDGES 3200000
#define HID 256
#define NG 16
#define BN_EPS 1e-5f
#define B0 120      // bn0stats partial blocks
#define PB 128      // stats partial blocks

typedef unsigned short u16;
using bf16x8 = __attribute__((ext_vector_type(8))) short;
using f32x4  = __attribute__((ext_vector_type(4))) float;

__device__ __forceinline__ float bf2f(u16 b) {
    return __uint_as_float(((unsigned)b) << 16);
}
__device__ __forceinline__ u16 f2bf(float f) {
    unsigned u = __float_as_uint(f);
    unsigned r = (u + 0x7FFFu + ((u >> 16) & 1u)) >> 16;
    return (u16)r;
}
__device__ __forceinline__ float4 ld_bf16x4(const u16* p) {
    ushort4 u = *reinterpret_cast<const ushort4*>(p);
    float4 f;
    f.x = bf2f(u.x); f.y = bf2f(u.y); f.z = bf2f(u.z); f.w = bf2f(u.w);
    return f;
}

// ---------------- CSR build ----------------
__global__ void k_count(const int* __restrict__ coli, int* __restrict__ cnt) {
    int i = blockIdx.x * blockDim.x + threadIdx.x;
    int st = gridDim.x * blockDim.x;
    for (; i < N_EDGES; i += st) atomicAdd(&cnt[coli[i]], 1);
}

__global__ void k_dinv(const int* __restrict__ cnt, float* __restrict__ dinv) {
    int i = blockIdx.x * blockDim.x + threadIdx.x;
    if (i < N_NODES) dinv[i] = rsqrtf((float)cnt[i] + 1.0f);
}

// 1024-thread single-block scan, wave-shuffle based
__global__ void k_scan(const int* __restrict__ cnt, int* __restrict__ ptr) {
    __shared__ int wsum[16];
    const int t = threadIdx.x;
    const int wv = t >> 6;
    const int ln = t & 63;
    int carry = 0;
    for (int base = 0; base < N_NODES; base += 4096) {
        int idx = base + t * 4;
        int v0 = 0, v1 = 0, v2 = 0, v3 = 0;
        if (idx + 3 < N_NODES) {
            int4 q = *reinterpret_cast<const int4*>(&cnt[idx]);
            v0 = q.x; v1 = q.y; v2 = q.z; v3 = q.w;
        } else {
            if (idx + 0 < N_NODES) v0 = cnt[idx + 0];
            if (idx + 1 < N_NODES) v1 = cnt[idx + 1];
            if (idx + 2 < N_NODES) v2 = cnt[idx + 2];
        }
        int s = v0 + v1 + v2 + v3;
        int sc = s;
        for (int off = 1; off < 64; off <<= 1) {
            int u = __shfl_up(sc, off);
            if (ln >= off) sc += u;
        }
        if (ln == 63) wsum[wv] = sc;
        __syncthreads();
        if (wv == 0 && ln < 16) {
            int a = wsum[ln];
            for (int off = 1; off < 16; off <<= 1) {
                int u = __shfl_up(a, off, 16);
                if (ln >= off) a += u;
            }
            wsum[ln] = a;
        }
        __syncthreads();
        int total = wsum[15];
        int excl = carry + (wv ? wsum[wv - 1] : 0) + sc - s;
        if (idx + 0 < N_NODES) ptr[idx + 0] = excl; excl += v0;
        if (idx + 1 < N_NODES) ptr[idx + 1] = excl; excl += v1;
        if (idx + 2 < N_NODES) ptr[idx + 2] = excl; excl += v2;
        if (idx + 3 < N_NODES) ptr[idx + 3] = excl;
        __syncthreads();
        carry += total;
    }
    if (t == 0) ptr[N_NODES] = carry;
}

__global__ void k_fill(const int* __restrict__ rowi, const int* __restrict__ coli,
                       const int* __restrict__ ptr, int* __restrict__ fc,
                       int* __restrict__ esrc) {
    int i = blockIdx.x * blockDim.x + threadIdx.x;
    int st = gridDim.x * blockDim.x;
    for (; i < N_EDGES; i += st) {
        int c = coli[i];
        int p = ptr[c] + atomicAdd(&fc[c], 1);
        esrc[p] = rowi[i];
    }
}

// per-block LDS histogram -> 16 global atomics per block
__global__ __launch_bounds__(256) void k_batchcnt(const int* __restrict__ batch,
                                                  int* __restrict__ cg) {
    __shared__ int h[NG];
    if (threadIdx.x < NG) h[threadIdx.x] = 0;
    __syncthreads();
    int i = blockIdx.x * blockDim.x + threadIdx.x;
    if (i < N_NODES) atomicAdd(&h[batch[i]], 1);
    __syncthreads();
    if (threadIdx.x < NG) {
        int v = h[threadIdx.x];
        if (v) atomicAdd(&cg[threadIdx.x], v);
    }
}

// ---------------- BN0 stats: block-reduced partials, NO global atomics ----------------
__global__ __launch_bounds__(256) void k_bn0stats(const float* __restrict__ pos,
                                                  const float* __restrict__ nrm,
                                                  float* __restrict__ part /* B0*12 */) {
    float s[6] = {0, 0, 0, 0, 0, 0}, q[6] = {0, 0, 0, 0, 0, 0};
    int i = blockIdx.x * blockDim.x + threadIdx.x;
    int stp = gridDim.x * blockDim.x;
    for (; i < N_NODES; i += stp) {
        float v;
        v = pos[i * 3 + 0]; s[0] += v; q[0] += v * v;
        v = pos[i * 3 + 1]; s[1] += v; q[1] += v * v;
        v = pos[i * 3 + 2]; s[2] += v; q[2] += v * v;
        v = nrm[i * 3 + 0]; s[3] += v; q[3] += v * v;
        v = nrm[i * 3 + 1]; s[4] += v; q[4] += v * v;
        v = nrm[i * 3 + 2]; s[5] += v; q[5] += v * v;
    }
#pragma unroll
    for (int k = 0; k < 6; ++k) {
        for (int o = 32; o > 0; o >>= 1) { s[k] += __shfl_down(s[k], o); q[k] += __shfl_down(q[k], o); }
    }
    __shared__ float ls[4][12];
    const int wv = threadIdx.x >> 6;
    const int ln = threadIdx.x & 63;
    if (ln == 0) {
#pragma unroll
        for (int k = 0; k < 6; ++k) { ls[wv][k] = s[k]; ls[wv][6 + k] = q[k]; }
    }
    __syncthreads();
    if (threadIdx.x < 12)
        part[blockIdx.x * 12 + threadIdx.x] =
            ls[0][threadIdx.x] + ls[1][threadIdx.x] + ls[2][threadIdx.x] + ls[3][threadIdx.x];
}

// ---------------- fold BN0 into W1 (K=6), reduces partials in preamble ----------------
__global__ void k_fold6(const float* __restrict__ W,
                        const float* __restrict__ part, float invcnt,
                        const float* __restrict__ gamma, const float* __restrict__ beta,
                        float* __restrict__ Wf, float* __restrict__ rv) {
    __shared__ float st[12];
    int c = threadIdx.x;
    if (c < 12) {
        float a = 0.f;
        for (int b = 0; b < B0; ++b) a += part[b * 12 + c];
        st[c] = a;
    }
    __syncthreads();
    float acc = 0.f;
    for (int k = 0; k < 6; ++k) {
        float m = st[k] * invcnt;
        float var = st[6 + k] * invcnt - m * m;
        float A = gamma[k] * rsqrtf(var + BN_EPS);
        float B = beta[k] - m * A;
        float w = W[k * HID + c];
        Wf[k * HID + c] = A * w;
        acc = fmaf(B, w, acc);
    }
    rv[c] = acc;
}

// ---------------- fold for K=256 (reduces stats partials in preamble) ----------------
__global__ void k_fold256(const float* __restrict__ W,
                          const float* __restrict__ part /* PB*512 */, float invcnt,
                          const float* __restrict__ gamma, const float* __restrict__ beta,
                          float* __restrict__ Wf, u16* __restrict__ WhiT,
                          u16* __restrict__ WloT, float* __restrict__ rv) {
    __shared__ float ss[HID], sq[HID];
    int c = threadIdx.x;
    {
        float a = 0.f, b = 0.f;
#pragma unroll 4
        for (int bb = 0; bb < PB; ++bb) {
            a += part[bb * 512 + c];
            b += part[bb * 512 + HID + c];
        }
        ss[c] = a; sq[c] = b;
    }
    __syncthreads();
    float acc = 0.f;
    for (int k = 0; k < HID; ++k) {
        float m = ss[k] * invcnt;
        float var = sq[k] * invcnt - m * m;
        float A = gamma[k] * rsqrtf(var + BN_EPS);
        float B = beta[k] - m * A;
        float w = W[k * HID + c];
        float wf = A * w;
        Wf[k * HID + c] = wf;
        u16 hi = f2bf(wf);
        WhiT[c * HID + k] = hi;
        WloT[c * HID + k] = f2bf(wf - bf2f(hi));
        acc = fmaf(B, w, acc);
    }
    rv[c] = acc;
}

// ---------------- layer-1 GEMM: [N,6](f32) @ [6,256] -> bf16 ----------------
__global__ __launch_bounds__(256) void k_gemm1(
    const float* __restrict__ pos, const float* __restrict__ nrm,
    const float* __restrict__ Wf, const float* __restrict__ rv,
    u16* __restrict__ out) {
    const int c = threadIdx.x;
    __shared__ float Ws[6 * HID];
    __shared__ float rvs[HID];
#pragma unroll
    for (int k = 0; k < 6; ++k) Ws[k * HID + c] = Wf[k * HID + c];
    rvs[c] = rv[c];
    __syncthreads();
    for (int n = blockIdx.x; n < N_NODES; n += gridDim.x) {
        float x0 = pos[n * 3 + 0], x1 = pos[n * 3 + 1], x2 = pos[n * 3 + 2];
        float x3 = nrm[n * 3 + 0], x4 = nrm[n * 3 + 1], x5 = nrm[n * 3 + 2];
        float acc = rvs[c];
        acc = fmaf(x0, Ws[0 * HID + c], acc);
        acc = fmaf(x1, Ws[1 * HID + c], acc);
        acc = fmaf(x2, Ws[2 * HID + c], acc);
        acc = fmaf(x3, Ws[3 * HID + c], acc);
        acc = fmaf(x4, Ws[4 * HID + c], acc);
        acc = fmaf(x5, Ws[5 * HID + c], acc);
        out[(size_t)n * HID + c] = f2bf(acc);
    }
}

// ---------------- MFMA GEMM: [N,256](bf16) @ (WhiT+WloT) + rv -> bf16 ----------------
__global__ __launch_bounds__(256) void k_gemm_mfma(
    const u16* __restrict__ X, const u16* __restrict__ WhiT,
    const u16* __restrict__ WloT, const float* __restrict__ rv,
    u16* __restrict__ out) {
    const int tid = threadIdx.x;
    const int wv = tid >> 6;
    const int ln = tid & 63;
    const int row0 = blockIdx.x * 64;
    const int lr = ln & 15;
    const int lk = (ln >> 4) * 8;
    const int wcol0 = wv * 64;

    f32x4 acc[4][4] = {};
    for (int kk = 0; kk < HID; kk += 32) {
        bf16x8 a[4], bh[4], bl[4];
#pragma unroll
        for (int i = 0; i < 4; ++i) {
            int r = row0 + i * 16 + lr;
            if (r >= N_NODES) r = N_NODES - 1;
            a[i] = *reinterpret_cast<const bf16x8*>(&X[(size_t)r * HID + kk + lk]);
        }
#pragma unroll
        for (int c = 0; c < 4; ++c) {
            int col = wcol0 + c * 16 + lr;
            bh[c] = *reinterpret_cast<const bf16x8*>(&WhiT[(size_t)col * HID + kk + lk]);
            bl[c] = *reinterpret_cast<const bf16x8*>(&WloT[(size_t)col * HID + kk + lk]);
        }
#pragma unroll
        for (int i = 0; i < 4; ++i)
#pragma unroll
            for (int c = 0; c < 4; ++c) {
                acc[i][c] = __builtin_amdgcn_mfma_f32_16x16x32_bf16(a[i], bh[c], acc[i][c], 0, 0, 0);
                acc[i][c] = __builtin_amdgcn_mfma_f32_16x16x32_bf16(a[i], bl[c], acc[i][c], 0, 0, 0);
            }
    }
    const int crow = (ln >> 4) * 4;
#pragma unroll
    for (int c = 0; c < 4; ++c) {
        int col = wcol0 + c * 16 + lr;
        float rvc = rv[col];
#pragma unroll
        for (int i = 0; i < 4; ++i) {
#pragma unroll
            for (int rg = 0; rg < 4; ++rg) {
                int r = row0 + i * 16 + crow + rg;
                if (r < N_NODES)
                    out[(size_t)r * HID + col] = f2bf(acc[i][c][rg] + rvc);
            }
        }
    }
}

// ---------------- spot-verify MFMA result; sets flag on mismatch ----------------
__global__ void k_gverify(const u16* __restrict__ X, const float* __restrict__ Wf,
                          const float* __restrict__ rv, const u16* __restrict__ out,
                          int* __restrict__ flag) {
    int t = threadIdx.x;
    int n = (t * 19391 + 7) % N_NODES;
    int c = (t * 151 + 3) & 255;
    float acc = rv[c];
    for (int k = 0; k < HID; ++k)
        acc = fmaf(bf2f(X[(size_t)n * HID + k]), Wf[k * HID + c], acc);
    float got = bf2f(out[(size_t)n * HID + c]);
    float tol = 0.02f * fabsf(acc) + 0.02f;
    if (fabsf(got - acc) > tol) atomicOr(flag, 1);
}

// ---------------- VALU fallback GEMM (runs only if flag set) ----------------
__global__ __launch_bounds__(256) void k_gemm_fb(
    const u16* __restrict__ X, const float* __restrict__ Wf,
    const float* __restrict__ rv, u16* __restrict__ out,
    const int* __restrict__ flag) {
    if (flag[0] == 0) return;
    __shared__ float As[64 * 128];
    const int tid = threadIdx.x;
    const int wv = tid >> 6;
    const int ln = tid & 63;
    const int row0 = blockIdx.x * 64;
    float acc[16][4];
#pragma unroll
    for (int i = 0; i < 16; ++i)
#pragma unroll
        for (int j = 0; j < 4; ++j) acc[i][j] = 0.f;

    for (int kb = 0; kb < 256; kb += 128) {
        __syncthreads();
#pragma unroll
        for (int i = 0; i < 8; ++i) {
            int idx = tid + i * 256;
            int r = idx >> 5;
            int k4 = (idx & 31) << 2;
            float4 v = make_float4(0.f, 0.f, 0.f, 0.f);
            if (row0 + r < N_NODES)
                v = ld_bf16x4(&X[(size_t)(row0 + r) * HID + kb + k4]);
            *reinterpret_cast<float4*>(&As[r * 128 + k4]) = v;
        }
        __syncthreads();
#pragma unroll 2
        for (int k = 0; k < 128; ++k) {
            float4 w = *reinterpret_cast<const float4*>(&Wf[(size_t)(kb + k) * HID + ln * 4]);
#pragma unroll
            for (int i = 0; i < 16; ++i) {
                float a = As[(wv * 16 + i) * 128 + k];
                acc[i][0] = fmaf(a, w.x, acc[i][0]);
                acc[i][1] = fmaf(a, w.y, acc[i][1]);
                acc[i][2] = fmaf(a, w.z, acc[i][2]);
                acc[i][3] = fmaf(a, w.w, acc[i][3]);
            }
        }
    }
    float4 rvv = *reinterpret_cast<const float4*>(&rv[ln * 4]);
#pragma unroll
    for (int i = 0; i < 16; ++i) {
        int r = row0 + wv * 16 + i;
        if (r < N_NODES) {
            ushort4 o;
            o.x = f2bf(acc[i][0] + rvv.x);
            o.y = f2bf(acc[i][1] + rvv.y);
            o.z = f2bf(acc[i][2] + rvv.z);
            o.w = f2bf(acc[i][3] + rvv.w);
            *reinterpret_cast<ushort4*>(&out[(size_t)r * HID + ln * 4]) = o;
        }
    }
}

// ---------------- aggregation: y = relu(agg + sl*xw + bias) ----------------
__global__ __launch_bounds__(256) void k_agg(
    const u16* __restrict__ xw, const int* __restrict__ ptr,
    const int* __restrict__ esrc, const float* __restrict__ dinv,
    const float* __restrict__ bias, u16* __restrict__ y) {
    const int wv = threadIdx.x >> 6;
    const int ln = threadIdx.x & 63;
    const int n = blockIdx.x * 4 + wv;
    const float dn = dinv[n];
    const size_t base = (size_t)n * HID + ln * 4;
    float4 v = ld_bf16x4(&xw[base]);
    const float sl = dn * dn;
    float a0 = v.x * sl, a1 = v.y * sl, a2 = v.z * sl, a3 = v.w * sl;
    const int s = ptr[n], e = ptr[n + 1];
#pragma unroll 2
    for (int i = s; i < e; ++i) {
        int src = esrc[i];
        float w = dinv[src] * dn;
        float4 u = ld_bf16x4(&xw[(size_t)src * HID + ln * 4]);
        a0 = fmaf(w, u.x, a0);
        a1 = fmaf(w, u.y, a1);
        a2 = fmaf(w, u.z, a2);
        a3 = fmaf(w, u.w, a3);
    }
    float4 b = *reinterpret_cast<const float4*>(&bias[ln * 4]);
    a0 = fmaxf(a0 + b.x, 0.f);
    a1 = fmaxf(a1 + b.y, 0.f);
    a2 = fmaxf(a2 + b.z, 0.f);
    a3 = fmaxf(a3 + b.w, 0.f);
    ushort4 o;
    o.x = f2bf(a0); o.y = f2bf(a1); o.z = f2bf(a2); o.w = f2bf(a3);
    *reinterpret_cast<ushort4*>(&y[base]) = o;
}

// ---------------- per-channel stats partials (no atomics) ----------------
__global__ __launch_bounds__(256) void k_stats(const u16* __restrict__ y,
                                               float* __restrict__ part /* PB*512 */) {
    const int c = threadIdx.x;
    float s = 0.f, q = 0.f;
    for (int n = blockIdx.x; n < N_NODES; n += gridDim.x) {
        float v = bf2f(y[(size_t)n * HID + c]);
        s += v;
        q = fmaf(v, v, q);
    }
    part[blockIdx.x * 512 + c] = s;
    part[blockIdx.x * 512 + HID + c] = q;
}

// ---------------- pooled sums by graph (batch is sorted) ----------------
__global__ __launch_bounds__(256) void k_pool(
    const u16* __restrict__ y, const int* __restrict__ batch,
    float* __restrict__ ps) {
    const int c = threadIdx.x;
    int r0 = blockIdx.x * 64;
    if (r0 >= N_NODES) return;
    int rend = (r0 + 64 < N_NODES) ? r0 + 64 : N_NODES;
    int cur = batch[r0];
    float acc = 0.f;
    for (int r = r0; r < rend; ++r) {
        int g = batch[r];
        if (g != cur) {
            atomicAdd(&ps[cur * HID + c], acc);
            acc = 0.f;
            cur = g;
        }
        acc += bf2f(y[(size_t)r * HID + c]);
    }
    atomicAdd(&ps[cur * HID + c], acc);
}

// ---------------- finalize: BN4 affine on pooled sums (reduces partials) ----------------
__global__ void k_final(const float* __restrict__ ps, const int* __restrict__ cg,
                        const float* __restrict__ part, const float* __restrict__ gamma,
                        const float* __restrict__ beta, float* __restrict__ out) {
    __shared__ float ss[HID], sq[HID];
    const int c = threadIdx.x;
    {
        float a = 0.f, b = 0.f;
#pragma unroll 4
        for (int bb = 0; bb < PB; ++bb) {
            a += part[bb * 512 + c];
            b += part[bb * 512 + HID + c];
        }
        ss[c] = a; sq[c] = b;
    }
    __syncthreads();
    const float invn = 1.0f / (float)N_NODES;
    float m = ss[c] * invn;
    float var = sq[c] * invn - m * m;
    float A = gamma[c] * rsqrtf(var + BN_EPS);
    float B = beta[c] - m * A;
    for (int g = 0; g < NG; ++g) {
        float cn = (float)cg[g];
        float val = (A * ps[g * HID + c] + cn * B) / fmaxf(cn, 1.0f);
        out[g * HID + c] = val;
    }
}

extern "C" void kernel_launch(void* const* d_in, const int* in_sizes, int n_in,
                              void* d_out, int out_size, void* d_ws, size_t ws_size,
                              hipStream_t stream) {
    const float* pos   = (const float*)d_in[0];
    const float* nrm   = (const float*)d_in[1];
    const int*   ei    = (const int*)d_in[2];
    const int*   batch = (const int*)d_in[3];
    const float* bn0g  = (const float*)d_in[4];
    const float* bn0b  = (const float*)d_in[5];
    const float* W[4]   = {(const float*)d_in[6],  (const float*)d_in[10], (const float*)d_in[14], (const float*)d_in[18]};
    const float* bb[4]  = {(const float*)d_in[7],  (const float*)d_in[11], (const float*)d_in[15], (const float*)d_in[19]};
    const float* bg[4]  = {(const float*)d_in[8],  (const float*)d_in[12], (const float*)d_in[16], (const float*)d_in[20]};
    const float* bbt[4] = {(const float*)d_in[9],  (const float*)d_in[13], (const float*)d_in[17], (const float*)d_in[21]};

    char* wp = (char*)d_ws;
    auto alloc = [&](size_t bytes) {
        char* p = wp;
        wp += (bytes + 255) & ~(size_t)255;
        return p;
    };
    float* dinv  = (float*)alloc((size_t)N_NODES * 4);
    int*   cnt   = (int*)  alloc((size_t)N_NODES * 4);
    int*   ptr   = (int*)  alloc((size_t)(N_NODES + 1) * 4);
    int*   esrc  = (int*)  alloc((size_t)N_EDGES * 4);
    u16*   bufA  = (u16*)  alloc((size_t)N_NODES * HID * 2);
    u16*   bufB  = (u16*)  alloc((size_t)N_NODES * HID * 2);
    float* part0 = (float*)alloc((size_t)B0 * 12 * 4);
    float* partL = (float*)alloc((size_t)PB * 512 * 4);
    float* Wf    = (float*)alloc((size_t)HID * HID * 4);
    u16*   WhiT  = (u16*)  alloc((size_t)HID * HID * 2);
    u16*   WloT  = (u16*)  alloc((size_t)HID * HID * 2);
    float* rv    = (float*)alloc(HID * 4);
    float* ps    = (float*)alloc(NG * HID * 4);
    int*   cg    = (int*)  alloc(NG * 4);
    int*   flag  = (int*)  alloc(4);
    (void)ws_size; (void)in_sizes; (void)n_in; (void)out_size;

    const int* rowi = ei;
    const int* coli = ei + N_EDGES;

    hipMemsetAsync(cnt, 0, (size_t)N_NODES * 4, stream);
    hipMemsetAsync(ps, 0, NG * HID * 4, stream);
    hipMemsetAsync(cg, 0, NG * 4, stream);

    k_count<<<2048, 256, 0, stream>>>(coli, cnt);
    k_dinv<<<(N_NODES + 255) / 256, 256, 0, stream>>>(cnt, dinv);
    k_scan<<<1, 1024, 0, stream>>>(cnt, ptr);
    hipMemsetAsync(cnt, 0, (size_t)N_NODES * 4, stream);
    k_fill<<<2048, 256, 0, stream>>>(rowi, coli, ptr, cnt, esrc);
    k_batchcnt<<<(N_NODES + 255) / 256, 256, 0, stream>>>(batch, cg);
    k_bn0stats<<<B0, 256, 0, stream>>>(pos, nrm, part0);
    k_fold6<<<1, 256, 0, stream>>>(W[0], part0, 1.0f / (float)N_NODES, bn0g, bn0b, Wf, rv);
    k_gemm1<<<4096, 256, 0, stream>>>(pos, nrm, Wf, rv, bufA);

    for (int l = 0; l < 4; ++l) {
        k_agg<<<N_NODES / 4, 256, 0, stream>>>(bufA, ptr, esrc, dinv, bb[l], bufB);
        k_stats<<<PB, 256, 0, stream>>>(bufB, partL);
        if (l < 3) {
            k_fold256<<<1, 256, 0, stream>>>(W[l + 1], partL, 1.0f / (float)N_NODES,
                                             bg[l], bbt[l], Wf, WhiT, WloT, rv);
            k_gemm_mfma<<<(N_NODES + 63) / 64, 256, 0, stream>>>(bufB, WhiT, WloT, rv, bufA);
            hipMemsetAsync(flag, 0, 4, stream);
            k_gverify<<<1, 128, 0, stream>>>(bufB, Wf, rv, bufA, flag);
            k_gemm_fb<<<(N_NODES + 63) / 64, 256, 0, stream>>>(bufB, Wf, rv, bufA, flag);
        } else {
            k_pool<<<(N_NODES + 63) / 64, 256, 0, stream>>>(bufB, batch, ps);
            k_final<<<1, 256, 0, stream>>>(ps, cg, partL, bg[l], bbt[l], (float*)d_out);
        }
    }
}